// Round 9
// baseline (5655.064 us; speedup 1.0000x reference)
//
#include <hip/hip_runtime.h>
#include <hip/hip_bf16.h>

#define H 1024
#define B3H 3072
#define BATCH 128
#define TSTEPS 256
#define LROW 520                 // 512 k-chunk + 8 pad (shorts)
#define PLANE32 (32 * LROW)      // one 32-row bf16 plane per chunk
#define NBLK 256
#define NTHR 768                 // 12 waves: (gate-pair ct) x (k-quarter kq)

typedef __attribute__((ext_vector_type(8))) short short8;
typedef __attribute__((ext_vector_type(4))) float f32x4;

static __device__ __forceinline__ float bf2f(__hip_bfloat16 v) { return __bfloat162float(v); }
static __device__ __forceinline__ unsigned short f2bf_bits(float f) {
    __hip_bfloat16 h = __float2bfloat16(f);
    return __builtin_bit_cast(unsigned short, h);
}
static __device__ __forceinline__ float bits2f(unsigned short b) {
    return bf2f(__builtin_bit_cast(__hip_bfloat16, b));
}
static __device__ __forceinline__ unsigned short bfbits(__hip_bfloat16 v) {
    return __builtin_bit_cast(unsigned short, v);
}
static __device__ __forceinline__ void split_bf(float v, unsigned short& hi, unsigned short& lo) {
    hi = f2bf_bits(v);
    lo = f2bf_bits(v - bits2f(hi));
}

// ws layout
#define BAR_OFF  128                       // 256 arrival slots (u32)
#define PW_OFF   2048
#define PWL_OFF  (PW_OFF + 12582912)
#define XHI_OFF  (PWL_OFF + 12582912)
#define XLO_OFF  (XHI_OFF + 262144)
#define H0HI_OFF (XLO_OFF + 262144)
#define H0LO_OFF (H0HI_OFF + 262144)
#define H1HI_OFF (H0LO_OFF + 262144)
#define H1LO_OFF (H1HI_OFF + 262144)

__global__ void detect_dtype(const unsigned int* __restrict__ w, int* __restrict__ flag) {
    __shared__ int cnt[256];
    int c = 0;
    for (int i = threadIdx.x; i < 4096; i += 256) {
        unsigned int v = (w[i] >> 8) & 0x7f;
        c += (v >= 0x33 && v <= 0x3f) ? 1 : 0;
    }
    cnt[threadIdx.x] = c;
    __syncthreads();
    for (int s = 128; s > 0; s >>= 1) {
        if (threadIdx.x < s) cnt[threadIdx.x] += cnt[threadIdx.x + s];
        __syncthreads();
    }
    if (threadIdx.x == 0) *flag = (cnt[0] * 2 > 4096) ? 1 : 0;
}

// Pack W into MFMA B-fragment layout, bf16 hi/lo pair (unchanged — verified).
__global__ void pack_w(const void* __restrict__ Kp, const void* __restrict__ Rp,
                       __hip_bfloat16* __restrict__ pwh, __hip_bfloat16* __restrict__ pwl,
                       const int* __restrict__ flag) {
    int idx = blockIdx.x * 256 + threadIdx.x;
    int lane = idx & 63;
    int kc   = (idx >> 6) & 31;
    int ns   = (idx >> 11) & 1;
    int it   = (idx >> 12) & 31;
    int g    = idx >> 17;
    if (g >= 6) return;
    const int isbf = *flag;
    int col   = (g % 3) * 1024 + it * 32 + ns * 16 + (lane & 15);
    int kbase = kc * 32 + (lane >> 4) * 8;
    unsigned short eh[8], el[8];
    if (isbf) {
        const __hip_bfloat16* src = (const __hip_bfloat16*)((g < 3) ? Kp : Rp);
#pragma unroll
        for (int j = 0; j < 8; ++j) { eh[j] = bfbits(src[(size_t)(kbase + j) * B3H + col]); el[j] = 0; }
    } else {
        const float* src = (const float*)((g < 3) ? Kp : Rp);
#pragma unroll
        for (int j = 0; j < 8; ++j) split_bf(src[(size_t)(kbase + j) * B3H + col], eh[j], el[j]);
    }
    uint4 vh, vl;
    vh.x = (unsigned int)eh[0] | ((unsigned int)eh[1] << 16);
    vh.y = (unsigned int)eh[2] | ((unsigned int)eh[3] << 16);
    vh.z = (unsigned int)eh[4] | ((unsigned int)eh[5] << 16);
    vh.w = (unsigned int)eh[6] | ((unsigned int)eh[7] << 16);
    vl.x = (unsigned int)el[0] | ((unsigned int)el[1] << 16);
    vl.y = (unsigned int)el[2] | ((unsigned int)el[3] << 16);
    vl.z = (unsigned int)el[4] | ((unsigned int)el[5] << 16);
    vl.w = (unsigned int)el[6] | ((unsigned int)el[7] << 16);
    *(uint4*)(pwh + (size_t)idx * 8) = vh;
    *(uint4*)(pwl + (size_t)idx * 8) = vl;
}

// Inputs -> pre-split bf16 hi/lo planes. Also zeroes the arrival slots.
__global__ void init_bufs(const void* __restrict__ cin, const void* __restrict__ hs,
                          unsigned short* __restrict__ xhi, unsigned short* __restrict__ xlo,
                          unsigned short* __restrict__ hhi, unsigned short* __restrict__ hlo,
                          unsigned int* __restrict__ bar,
                          const int* __restrict__ flag) {
    int i = blockIdx.x * 256 + threadIdx.x;
    if (blockIdx.x == 0 && threadIdx.x < 480) bar[threadIdx.x] = 0;
    if (i >= BATCH * H) return;
    float xv, hv;
    if (*flag) {
        xv = bf2f(((const __hip_bfloat16*)cin)[i]);
        hv = bf2f(((const __hip_bfloat16*)hs)[i]);
    } else {
        xv = ((const float*)cin)[i];
        hv = ((const float*)hs)[i];
    }
    unsigned short a, b;
    split_bf(xv, a, b); xhi[i] = a; xlo[i] = b;
    split_bf(hv, a, b); hhi[i] = a; hlo[i] = b;
}

// ---------------------------------------------------------------------------
// Persistent GRU. R9 = R8 geometry (32-row tiles, 4bt x 64it) with waves
// re-paired as (gate-pair ct 0..2) x (k-quarter kq 0..3): each wave reads ONE
// set of A fragments per kcg and feeds TWO gates' B streams (12 MFMA/kcg).
// A-read redundancy drops 6 -> 3: GEMM LDS traffic 768 -> 384 KB/CU/step
// (R8's dominant term: 2.56 µs min + 1.45 µs conflicts). B prologue prefetch
// hoisted above staging (weights are t-invariant) to hide L2 latency under
// the staging MALL wait. t=0: per-gate A base (x for gates 0-2, h for 3-5),
// chunked as in R8. sG = 48 per-gate 16x18-padded f32 tiles (55 KB).
// ---------------------------------------------------------------------------
__launch_bounds__(NTHR, 1)
__global__ void gru_persistent(const unsigned short* __restrict__ xhi,
                               const unsigned short* __restrict__ xlo,
                               unsigned short* __restrict__ h0hi,
                               unsigned short* __restrict__ h0lo,
                               unsigned short* __restrict__ h1hi,
                               unsigned short* __restrict__ h1lo,
                               const __hip_bfloat16* __restrict__ pwh,
                               const __hip_bfloat16* __restrict__ pwl,
                               const void* __restrict__ bias,
                               void* __restrict__ out,
                               unsigned int* __restrict__ bar,
                               const int* __restrict__ flag) {
    // steady planes: 0=c0hi 1=c0lo 2=c1hi 3=c1lo; t=0 per chunk: 0=xhi 1=xlo 2=hhi 3=hlo
    __shared__ unsigned short sA[4 * PLANE32];  // 133120 B (aliased by sG post-GEMM)
    __shared__ float sHold[512];                // 32 rows x 16 cols, full f32
    __shared__ float sBias[96];                 // 6 gates x 16 cols

    const int tid  = threadIdx.x;
    const int w    = tid >> 6;        // wave 0..11
    const int ctp  = w >> 2;          // gate pair: gates 2ctp, 2ctp+1
    const int kq   = w & 3;           // k-quarter (256 k)
    const int ga   = 2 * ctp;
    const int gb   = 2 * ctp + 1;
    const int lane = tid & 63;
    const int bt = blockIdx.x >> 6;   // 0..3, 32-row tiles (= sync group)
    const int it = blockIdx.x & 63;   // 0..63, 16-col slices (XCD = it%8)
    const int bbase = bt * 32;
    const int m0 = lane & 15;
    const int q  = lane >> 4;
    const int ibase0 = it * 16;
    const int isbf = *flag;

    // preload bias once
    {
        const __hip_bfloat16* bias_b = (const __hip_bfloat16*)bias;
        const float* bias_f = (const float*)bias;
        if (tid < 96) {
            int gg = tid >> 4;
            int i  = ibase0 + (tid & 15);
            int src = (gg < 3) ? (gg * 1024 + i) : (B3H + (gg - 3) * 1024 + i);
            sBias[tid] = isbf ? bf2f(bias_b[src]) : bias_f[src];
        }
    }

    // B streams for the two gates of this wave (16 cols each; kcg-indexed frags)
    const int it2 = it >> 1, ns = it & 1;
    const size_t boffA = ((size_t)((ga * 32 + it2) * 2 + ns) * 32) * 64 + lane;
    const size_t boffB = ((size_t)((gb * 32 + it2) * 2 + ns) * 32) * 64 + lane;
    const uint4* bhA = (const uint4*)pwh + boffA;
    const uint4* blA = (const uint4*)pwl + boffA;
    const uint4* bhB = (const uint4*)pwh + boffB;
    const uint4* blB = (const uint4*)pwl + boffB;
    const int kcg0 = kq * 8;

    __hip_bfloat16* outb = (__hip_bfloat16*)out;
    float* outf = (float*)out;

    for (int t = 0; t < TSTEPS; ++t) {
        const int cur = t & 1;
        const unsigned short* curhi = cur ? h1hi : h0hi;
        const unsigned short* curlo = cur ? h1lo : h0lo;
        unsigned short* dsthi = cur ? h0hi : h1hi;
        unsigned short* dstlo = cur ? h0lo : h1lo;

        f32x4 acc_a0 = {0.f, 0.f, 0.f, 0.f};   // gate ga, rows  0..15
        f32x4 acc_a1 = {0.f, 0.f, 0.f, 0.f};   // gate ga, rows 16..31
        f32x4 acc_b0 = {0.f, 0.f, 0.f, 0.f};   // gate gb, rows  0..15
        f32x4 acc_b1 = {0.f, 0.f, 0.f, 0.f};   // gate gb, rows 16..31

        if (t == 0) {
            // ---- t=0 (once): per-chunk stage {x hi/lo, h hi/lo}; per-gate A base ----
            for (int c = 0; c < 2; ++c) {
                if (c) __syncthreads();
                for (int gi = tid; gi < 8192; gi += NTHR) {
                    int plane = gi >> 11;     // 0=xhi 1=xlo 2=hhi 3=hlo
                    int rem   = gi & 2047;
                    int row   = rem >> 6;
                    int kg    = rem & 63;
                    const unsigned short* src =
                        (plane == 0) ? xhi : (plane == 1) ? xlo : (plane == 2) ? curhi : curlo;
                    uint4 v = *(const uint4*)&src[(size_t)(bbase + row) * H + c * 512 + kg * 8];
                    *(uint4*)&sA[plane * PLANE32 + row * LROW + kg * 8] = v;
                }
                __syncthreads();
                if ((kq >> 1) == c) {
                    const int baseA_ = (ga < 3) ? 0 : 2 * PLANE32;
                    const int baseB_ = (gb < 3) ? 0 : 2 * PLANE32;
#pragma unroll 2
                    for (int kc = 0; kc < 8; ++kc) {
                        const int kcg = kcg0 + kc;
                        short8 Bha = __builtin_bit_cast(short8, bhA[(size_t)kcg * 64]);
                        short8 Bla = __builtin_bit_cast(short8, blA[(size_t)kcg * 64]);
                        short8 Bhb = __builtin_bit_cast(short8, bhB[(size_t)kcg * 64]);
                        short8 Blb = __builtin_bit_cast(short8, blB[(size_t)kcg * 64]);
                        const int koff = ((kq & 1) * 8 + kc) * 32 + q * 8;
                        short8 aha0 = *(const short8*)&sA[baseA_ + m0 * LROW + koff];
                        short8 ala0 = *(const short8*)&sA[baseA_ + PLANE32 + m0 * LROW + koff];
                        short8 aha1 = *(const short8*)&sA[baseA_ + (16 + m0) * LROW + koff];
                        short8 ala1 = *(const short8*)&sA[baseA_ + PLANE32 + (16 + m0) * LROW + koff];
                        short8 ahb0 = *(const short8*)&sA[baseB_ + m0 * LROW + koff];
                        short8 alb0 = *(const short8*)&sA[baseB_ + PLANE32 + m0 * LROW + koff];
                        short8 ahb1 = *(const short8*)&sA[baseB_ + (16 + m0) * LROW + koff];
                        short8 alb1 = *(const short8*)&sA[baseB_ + PLANE32 + (16 + m0) * LROW + koff];
                        acc_a0 = __builtin_amdgcn_mfma_f32_16x16x32_bf16(aha0, Bha, acc_a0, 0, 0, 0);
                        acc_a0 = __builtin_amdgcn_mfma_f32_16x16x32_bf16(aha0, Bla, acc_a0, 0, 0, 0);
                        acc_a0 = __builtin_amdgcn_mfma_f32_16x16x32_bf16(ala0, Bha, acc_a0, 0, 0, 0);
                        acc_a1 = __builtin_amdgcn_mfma_f32_16x16x32_bf16(aha1, Bha, acc_a1, 0, 0, 0);
                        acc_a1 = __builtin_amdgcn_mfma_f32_16x16x32_bf16(aha1, Bla, acc_a1, 0, 0, 0);
                        acc_a1 = __builtin_amdgcn_mfma_f32_16x16x32_bf16(ala1, Bha, acc_a1, 0, 0, 0);
                        acc_b0 = __builtin_amdgcn_mfma_f32_16x16x32_bf16(ahb0, Bhb, acc_b0, 0, 0, 0);
                        acc_b0 = __builtin_amdgcn_mfma_f32_16x16x32_bf16(ahb0, Blb, acc_b0, 0, 0, 0);
                        acc_b0 = __builtin_amdgcn_mfma_f32_16x16x32_bf16(alb0, Bhb, acc_b0, 0, 0, 0);
                        acc_b1 = __builtin_amdgcn_mfma_f32_16x16x32_bf16(ahb1, Bhb, acc_b1, 0, 0, 0);
                        acc_b1 = __builtin_amdgcn_mfma_f32_16x16x32_bf16(ahb1, Blb, acc_b1, 0, 0, 0);
                        acc_b1 = __builtin_amdgcn_mfma_f32_16x16x32_bf16(alb1, Bhb, acc_b1, 0, 0, 0);
                    }
                }
            }
        } else {
            // ---- B prologue prefetch FIRST (t-invariant addrs; hides under staging) ----
            uint4 phA[4], plA[4], phB[4], plB[4];
#pragma unroll
            for (int p = 0; p < 4; ++p) {
                phA[p] = bhA[(size_t)(kcg0 + p) * 64];
                plA[p] = blA[(size_t)(kcg0 + p) * 64];
                phB[p] = bhB[(size_t)(kcg0 + p) * 64];
                plB[p] = blB[(size_t)(kcg0 + p) * 64];
            }

            // ---- batched device-coherent staging (non-atomic sc0 sc1), R8 verbatim ----
            const unsigned short* gp[11];
            int ld[11];
#pragma unroll
            for (int r2 = 0; r2 < 11; ++r2) {
                int gi = r2 * NTHR + tid;
                if (gi >= 8192) gi -= 8192;
                int plane = gi >> 11;
                int rem   = gi & 2047;
                int row   = rem >> 6;
                int kg    = rem & 63;
                const unsigned short* src = (plane & 1) ? curlo : curhi;
                gp[r2] = &src[(size_t)(bbase + row) * H + (plane >> 1) * 512 + kg * 8];
                ld[r2] = plane * PLANE32 + row * LROW + kg * 8;
            }
            uint4 v0, v1, v2, v3, v4, v5, v6, v7, v8, v9, v10;
            asm volatile(
                "global_load_dwordx4 %0, %11, off sc0 sc1\n\t"
                "global_load_dwordx4 %1, %12, off sc0 sc1\n\t"
                "global_load_dwordx4 %2, %13, off sc0 sc1\n\t"
                "global_load_dwordx4 %3, %14, off sc0 sc1\n\t"
                "global_load_dwordx4 %4, %15, off sc0 sc1\n\t"
                "global_load_dwordx4 %5, %16, off sc0 sc1\n\t"
                "global_load_dwordx4 %6, %17, off sc0 sc1\n\t"
                "global_load_dwordx4 %7, %18, off sc0 sc1\n\t"
                "global_load_dwordx4 %8, %19, off sc0 sc1\n\t"
                "global_load_dwordx4 %9, %20, off sc0 sc1\n\t"
                "global_load_dwordx4 %10, %21, off sc0 sc1\n\t"
                "s_waitcnt vmcnt(0)"
                : "=&v"(v0), "=&v"(v1), "=&v"(v2), "=&v"(v3), "=&v"(v4), "=&v"(v5),
                  "=&v"(v6), "=&v"(v7), "=&v"(v8), "=&v"(v9), "=&v"(v10)
                : "v"(gp[0]), "v"(gp[1]), "v"(gp[2]), "v"(gp[3]), "v"(gp[4]), "v"(gp[5]),
                  "v"(gp[6]), "v"(gp[7]), "v"(gp[8]), "v"(gp[9]), "v"(gp[10])
                : "memory");
            *(uint4*)&sA[ld[0]]  = v0;
            *(uint4*)&sA[ld[1]]  = v1;
            *(uint4*)&sA[ld[2]]  = v2;
            *(uint4*)&sA[ld[3]]  = v3;
            *(uint4*)&sA[ld[4]]  = v4;
            *(uint4*)&sA[ld[5]]  = v5;
            *(uint4*)&sA[ld[6]]  = v6;
            *(uint4*)&sA[ld[7]]  = v7;
            *(uint4*)&sA[ld[8]]  = v8;
            *(uint4*)&sA[ld[9]]  = v9;
            *(uint4*)&sA[ld[10]] = v10;
            __syncthreads();

            // ---- 8-kcg loop: 1x A-read set feeds 2 gates (12 MFMA/kcg) ----
#pragma unroll
            for (int kc = 0; kc < 8; ++kc) {
                const int kcg = kcg0 + kc;
                const int s = kc & 3;
                short8 Bha = __builtin_bit_cast(short8, phA[s]);
                short8 Bla = __builtin_bit_cast(short8, plA[s]);
                short8 Bhb = __builtin_bit_cast(short8, phB[s]);
                short8 Blb = __builtin_bit_cast(short8, plB[s]);
                if (kc + 4 < 8) {
                    phA[s] = bhA[(size_t)(kcg + 4) * 64];
                    plA[s] = blA[(size_t)(kcg + 4) * 64];
                    phB[s] = bhB[(size_t)(kcg + 4) * 64];
                    plB[s] = blB[(size_t)(kcg + 4) * 64];
                }
                const int base = (kcg >> 4) * 2 * PLANE32;
                const int koff = (kcg & 15) * 32 + q * 8;
                short8 ah0 = *(const short8*)&sA[base + m0 * LROW + koff];
                short8 al0 = *(const short8*)&sA[base + PLANE32 + m0 * LROW + koff];
                short8 ah1 = *(const short8*)&sA[base + (16 + m0) * LROW + koff];
                short8 al1 = *(const short8*)&sA[base + PLANE32 + (16 + m0) * LROW + koff];
                acc_a0 = __builtin_amdgcn_mfma_f32_16x16x32_bf16(ah0, Bha, acc_a0, 0, 0, 0);
                acc_a0 = __builtin_amdgcn_mfma_f32_16x16x32_bf16(ah0, Bla, acc_a0, 0, 0, 0);
                acc_a0 = __builtin_amdgcn_mfma_f32_16x16x32_bf16(al0, Bha, acc_a0, 0, 0, 0);
                acc_a1 = __builtin_amdgcn_mfma_f32_16x16x32_bf16(ah1, Bha, acc_a1, 0, 0, 0);
                acc_a1 = __builtin_amdgcn_mfma_f32_16x16x32_bf16(ah1, Bla, acc_a1, 0, 0, 0);
                acc_a1 = __builtin_amdgcn_mfma_f32_16x16x32_bf16(al1, Bha, acc_a1, 0, 0, 0);
                acc_b0 = __builtin_amdgcn_mfma_f32_16x16x32_bf16(ah0, Bhb, acc_b0, 0, 0, 0);
                acc_b0 = __builtin_amdgcn_mfma_f32_16x16x32_bf16(ah0, Blb, acc_b0, 0, 0, 0);
                acc_b0 = __builtin_amdgcn_mfma_f32_16x16x32_bf16(al0, Bhb, acc_b0, 0, 0, 0);
                acc_b1 = __builtin_amdgcn_mfma_f32_16x16x32_bf16(ah1, Bhb, acc_b1, 0, 0, 0);
                acc_b1 = __builtin_amdgcn_mfma_f32_16x16x32_bf16(ah1, Blb, acc_b1, 0, 0, 0);
                acc_b1 = __builtin_amdgcn_mfma_f32_16x16x32_bf16(al1, Bhb, acc_b1, 0, 0, 0);
            }
        }

        __syncthreads();
        // sG: 48 tiles [gate 0..5][kq 0..3][rt 0..1] of 16x18 f32 = 55296 B (aliases sA)
        float* sG = (float*)sA;
        {
            // C/D layout: col = lane&15, row = (lane>>4)*4 + reg  [m89/m91 verified]
#pragma unroll
            for (int r = 0; r < 4; ++r) {
                int row = q * 4 + r;
                sG[((ga * 4 + kq) * 2 + 0) * 288 + row * 18 + m0] = acc_a0[r];
                sG[((ga * 4 + kq) * 2 + 1) * 288 + row * 18 + m0] = acc_a1[r];
                sG[((gb * 4 + kq) * 2 + 0) * 288 + row * 18 + m0] = acc_b0[r];
                sG[((gb * 4 + kq) * 2 + 1) * 288 + row * 18 + m0] = acc_b1[r];
            }
        }
        __syncthreads();

        // epilogue: 256 threads x 2 adjacent cols (packed u32 h' stores)
        if (tid < 256) {
            const int e0   = tid * 2;
            const int mloc = e0 >> 4;          // 0..31
            const int nl0  = e0 & 15;          // even
            const int rt   = mloc >> 4;
            const int rr   = mloc & 15;
            const int b    = bbase + mloc;
            const int i0   = ibase0 + nl0;
            const size_t hidx0 = (size_t)b * H + i0;
            float hn[2];
            unsigned short nh[2], nl[2];
#pragma unroll
            for (int j = 0; j < 2; ++j) {
                const int c = nl0 + j;
                const int rbase = rr * 18 + c;
#define GV(g) (sG[(((g) * 4 + 0) * 2 + rt) * 288 + rbase] + sG[(((g) * 4 + 1) * 2 + rt) * 288 + rbase] \
             + sG[(((g) * 4 + 2) * 2 + rt) * 288 + rbase] + sG[(((g) * 4 + 3) * 2 + rt) * 288 + rbase])
                float xz = GV(0), xr = GV(1), xh = GV(2);
                float hz = GV(3), hr = GV(4), hh = GV(5);
#undef GV
                float zlin = xz + sBias[c]      + hz + sBias[48 + c];
                float rlin = xr + sBias[16 + c] + hr + sBias[64 + c];
                float xht  = xh + sBias[32 + c];
                float hht  = hh + sBias[80 + c];   // recurrent bias INSIDE r*(...)
                float z  = 1.0f / (1.0f + expf(-zlin));
                float r  = 1.0f / (1.0f + expf(-rlin));
                float hc = tanhf(xht + r * hht);
                const int e = e0 + j;
                float hold = t ? sHold[e]
                               : (bits2f(curhi[hidx0 + j]) + bits2f(curlo[hidx0 + j]));
                float hnew = z * hold + (1.0f - z) * hc;
                sHold[e] = hnew;
                hn[j] = hnew;
                split_bf(hnew, nh[j], nl[j]);
            }
            if (t < TSTEPS - 1) {
                unsigned int hiw = (unsigned int)nh[0] | ((unsigned int)nh[1] << 16);
                unsigned int low = (unsigned int)nl[0] | ((unsigned int)nl[1] << 16);
                __hip_atomic_store((unsigned int*)&dsthi[hidx0], hiw,
                                   __ATOMIC_RELAXED, __HIP_MEMORY_SCOPE_AGENT);
                __hip_atomic_store((unsigned int*)&dstlo[hidx0], low,
                                   __ATOMIC_RELAXED, __HIP_MEMORY_SCOPE_AGENT);
            }
            const size_t o1 = (size_t)b * (TSTEPS * H) + (size_t)t * H + i0;
            if (isbf) {
                outb[o1]     = __float2bfloat16(hn[0]);
                outb[o1 + 1] = __float2bfloat16(hn[1]);
                if (t == TSTEPS - 1) {
                    outb[(size_t)BATCH * TSTEPS * H + hidx0]     = __float2bfloat16(hn[0]);
                    outb[(size_t)BATCH * TSTEPS * H + hidx0 + 1] = __float2bfloat16(hn[1]);
                }
            } else {
                outf[o1]     = hn[0];
                outf[o1 + 1] = hn[1];
                if (t == TSTEPS - 1) {
                    outf[(size_t)BATCH * TSTEPS * H + hidx0]     = hn[0];
                    outf[(size_t)BATCH * TSTEPS * H + hidx0 + 1] = hn[1];
                }
            }
        }

        // ---- per-bt-group arrival-array barrier (4 groups of 64 blocks) ----
        if (t < TSTEPS - 1) {
            asm volatile("s_waitcnt vmcnt(0)" ::: "memory");  // own h' stores acked
            __syncthreads();
            if (tid == 0) {
                __hip_atomic_store(&bar[bt * 64 + it], (unsigned int)(t + 1),
                                   __ATOMIC_RELAXED, __HIP_MEMORY_SCOPE_AGENT);
            }
            if (w == 0) {
                const unsigned int target = (unsigned int)(t + 1);
                for (;;) {
                    unsigned int v = __hip_atomic_load(&bar[bt * 64 + lane],
                                        __ATOMIC_RELAXED, __HIP_MEMORY_SCOPE_AGENT);
                    if (__all(v >= target)) break;
                    __builtin_amdgcn_s_sleep(1);
                }
            }
            __syncthreads();
        }
    }
}

extern "C" void kernel_launch(void* const* d_in, const int* in_sizes, int n_in,
                              void* d_out, int out_size, void* d_ws, size_t ws_size,
                              hipStream_t stream) {
    const void* cin  = d_in[0];
    const void* hs   = d_in[1];
    const void* Kw   = d_in[2];
    const void* Rw   = d_in[3];
    const void* bias = d_in[4];

    char* ws = (char*)d_ws;
    int* flag = (int*)ws;
    unsigned int* bar = (unsigned int*)(ws + BAR_OFF);
    __hip_bfloat16* pwh = (__hip_bfloat16*)(ws + PW_OFF);
    __hip_bfloat16* pwl = (__hip_bfloat16*)(ws + PWL_OFF);
    unsigned short* xhi  = (unsigned short*)(ws + XHI_OFF);
    unsigned short* xlo  = (unsigned short*)(ws + XLO_OFF);
    unsigned short* h0hi = (unsigned short*)(ws + H0HI_OFF);
    unsigned short* h0lo = (unsigned short*)(ws + H0LO_OFF);
    unsigned short* h1hi = (unsigned short*)(ws + H1HI_OFF);
    unsigned short* h1lo = (unsigned short*)(ws + H1LO_OFF);

    detect_dtype<<<1, 256, 0, stream>>>((const unsigned int*)Kw, flag);
    pack_w<<<3072, 256, 0, stream>>>(Kw, Rw, pwh, pwl, flag);
    init_bufs<<<512, 256, 0, stream>>>(cin, hs, xhi, xlo, h0hi, h0lo, bar, flag);

    const unsigned short* xhi_c = xhi;
    const unsigned short* xlo_c = xlo;
    const __hip_bfloat16* pwh_c = pwh;
    const __hip_bfloat16* pwl_c = pwl;
    const int* flag_c = flag;
    void* kargs[] = {
        (void*)&xhi_c, (void*)&xlo_c,
        (void*)&h0hi, (void*)&h0lo, (void*)&h1hi, (void*)&h1lo,
        (void*)&pwh_c, (void*)&pwl_c,
        (void*)&bias, (void*)&d_out, (void*)&bar, (void*)&flag_c
    };
    hipLaunchCooperativeKernel((void*)gru_persistent, dim3(256), dim3(NTHR),
                               kargs, 0, stream);
}